// Round 5
// 180.095 us; speedup vs baseline: 1.0005x; 1.0005x over previous
//
#include <hip/hip_runtime.h>

#define LAMC    10000.0f
#define INV_LAM 1e-4f
#define EPSC    1e-12f
#define TOLC    1e-6f
#define BLK     256
#define WPB     (BLK / 64)   // waves per block

__device__ __forceinline__ float frcp(float x)  { return __builtin_amdgcn_rcpf(x); }
__device__ __forceinline__ float frsq(float x)  { return __builtin_amdgcn_rsqf(x); }
__device__ __forceinline__ float fsqrt_(float x){ return __builtin_amdgcn_sqrtf(x); }

// sign(phi(t)) without sqrt/div: phi = L - R*sqrt(q), q >= EPS > 0
__device__ __forceinline__ bool phi_pos(float t, float A, float p, float N, float b) {
    float q  = fmaxf(fmaf(t, fmaf(t, A, -2.0f * p), N), EPSC);
    float L  = fmaf(-t, A, p);        // p - t*A   (U_MAX = 1)
    float R  = fmaf(t, INV_LAM, b);   // b + t/LAM
    float L2 = L * L;
    float Rq = (R * R) * q;
    return (R < 0.0f) ? ((L >= 0.0f) || (L2 < Rq))
                      : ((L >  0.0f) && (L2 > Rq));
}

// branch-3 solve with proven tight bracket (phi has a unique sign change):
//  - p>0, R(p/A)>=0 : root in (0, p/A]
//  - p>0, R(p/A)<0  : root in (p/A, -lam*b)
//  - p<=0 (=> b<0)  : root in (0, -lam*b)
// GEOMETRIC bisection: mid = sqrt(max(lo,1e-6*hi)*hi). Any interior probe
// preserves the bracket invariant (verified signs only -> always valid),
// but convergence is multiplicative: 8 iters collapse a 1e6-ratio bracket
// to <=1.1x (and the floor descends 3 decades/iter while lo==0, so tiny
// roots are found FASTER than with linear mids). 5 safeguarded Newtons
// (exact R0 form) then converge fully in fp32.
__device__ __forceinline__ float2 heavy_solve(float ux, float uy,
                                              float ax, float ay, float b) {
    float A = fmaf(ax, ax, ay * ay);
    float p = fmaf(ax, ux, ay * uy);
    float N = fmaf(ux, ux, uy * uy);
    float t3;
    if (phi_pos(0.0f, A, p, N, b)) {
        float lo, hi;
        if (p > 0.0f) {
            float tA = p * frcp(fmaxf(A, 1e-30f));
            if (fmaf(tA, INV_LAM, b) >= 0.0f) { lo = 0.0f; hi = tA; }
            else                              { lo = tA;  hi = -LAMC * b; }
        } else {
            lo = 0.0f; hi = -LAMC * b;
        }
        #pragma unroll 1
        for (int k = 0; k < 8; ++k) {          // geometric bisection
            float fl  = fmaxf(lo, 1e-6f * hi);
            float mid = fsqrt_(fl * hi);
            bool pos = phi_pos(mid, A, p, N, b);
            lo = pos ? mid : lo;
            hi = pos ? hi : mid;
        }
        t3 = 0.5f * (lo + hi);
        #pragma unroll
        for (int k = 0; k < 5; ++k) {          // safeguarded Newton (R0 form)
            float q   = fmaxf(fmaf(t3, fmaf(t3, A, -2.0f * p), N), EPSC);
            float nrm = fsqrt_(q);
            float R   = fmaf(t3, INV_LAM, b);
            float f   = fmaf(-t3, A, p) - R * nrm;
            float df  = -A - nrm * INV_LAM - R * fmaf(t3, A, -p) * frcp(nrm);
            df = (fabsf(df) > 1e-8f) ? df : -1e-8f;
            bool fp = f > 0.0f;                // phi(t3)>0 -> root above t3
            lo = fp ? t3 : lo;
            hi = fp ? hi : t3;
            t3 = fminf(fmaxf(t3 - f * frcp(df), lo), hi);
        }
    } else {
        // reference: bisection collapses to 0, then 3 unclamped Newton steps
        t3 = 0.0f;
        #pragma unroll
        for (int k = 0; k < 3; ++k) {
            float q   = fmaxf(fmaf(t3, fmaf(t3, A, -2.0f * p), N), EPSC);
            float nrm = fsqrt_(q);
            float R   = fmaf(t3, INV_LAM, b);
            float f   = fmaf(-t3, A, p) - R * nrm;
            float df  = -A - nrm * INV_LAM - R * fmaf(t3, A, -p) * frcp(nrm);
            df = (fabsf(df) > 1e-8f) ? df : -1e-8f;
            t3 = t3 - f * frcp(df);
        }
    }
    float q3  = fmaxf(fmaf(t3, fmaf(t3, A, -2.0f * p), N), EPSC);
    float k3  = fmaxf(fsqrt_(q3), 1.0f);
    float inv = frcp(k3);
    return make_float2(fmaf(-t3, ax, ux) * inv, fmaf(-t3, ay, uy) * inv);
}

// easy paths; a,b precomputed by caller. returns true if heavy (branch 3).
__device__ __forceinline__ bool easy_row(float ux, float uy,
                                         float ax, float ay, float b,
                                         float& ox, float& oy) {
    float A  = fmaf(ax, ax, ay * ay);
    float p  = fmaf(ax, ux, ay * uy);
    float N  = fmaf(ux, ux, uy * uy);
    float s1 = fminf(1.0f, frsq(fmaxf(N, EPSC)));   // min(1, 1/|u|)
    float u1x = ux * s1, u1y = uy * s1;
    ox = u1x; oy = u1y;
    if (fmaf(ax, u1x, ay * u1y) <= b + TOLC) return false;
    float t2  = LAMC * (p - b) * frcp(fmaf(LAMC, A, 1.0f));
    float u2x = fmaf(-t2, ax, ux), u2y = fmaf(-t2, ay, uy);
    if (t2 >= -TOLC && fmaf(u2x, u2x, u2y * u2y) <= 1.0f + TOLC) {
        ox = u2x; oy = u2y; return false;
    }
    return true;
}

__global__ __launch_bounds__(BLK) void cbf_kernel(const float4* __restrict__ u4,
                                                  const float4* __restrict__ obs4,
                                                  float4* __restrict__ out4,
                                                  int npair) {
    __shared__ float4 sdat[WPB][128];   // compacted heavy inputs: ux,uy,ax,ay
    __shared__ float  sbv [WPB][128];   // compacted heavy b
    __shared__ float2 sres[WPB][128];   // heavy results by slot

    int tid  = threadIdx.x;
    int wave = tid >> 6;
    int lane = tid & 63;
    unsigned long long ltmask = (1ull << lane) - 1ull;

    int i = blockIdx.x * BLK + tid;
    bool valid = i < npair;
    float4 u  = make_float4(0.f, 0.f, 0.f, 0.f);
    float4 o0 = u, o1 = u, o2 = u;
    if (valid) {
        u  = u4[i];
        o0 = obs4[3 * i + 0];
        o1 = obs4[3 * i + 1];
        o2 = obs4[3 * i + 2];
    }
    // row 2i:   p=(o0.z,o0.w)  v=(o1.x,o1.y)
    // row 2i+1: p=(o2.x,o2.y)  v=(o2.z,o2.w)
    float ax0 = -2.0f * o0.z, ay0 = -2.0f * o0.w;
    float h0f = fmaf(o0.z, o0.z, o0.w * o0.w) - 1.0f;
    float b0  = fmaf(2.0f, h0f, -2.0f * fmaf(o0.z, o1.x, o0.w * o1.y));
    float ax1 = -2.0f * o2.x, ay1 = -2.0f * o2.y;
    float h1f = fmaf(o2.x, o2.x, o2.y * o2.y) - 1.0f;
    float b1  = fmaf(2.0f, h1f, -2.0f * fmaf(o2.x, o2.z, o2.y * o2.w));

    float4 r = make_float4(0.f, 0.f, 0.f, 0.f);
    bool h0 = false, h1 = false;
    if (valid) {
        h0 = easy_row(u.x, u.y, ax0, ay0, b0, r.x, r.y);
        h1 = easy_row(u.z, u.w, ax1, ay1, b1, r.z, r.w);
    }

    // wave-local ballot compaction — stage INPUTS in LDS (no global re-reads)
    unsigned long long m0 = __ballot(h0);
    unsigned long long m1 = __ballot(h1);
    int c0  = __popcll(m0);
    int tot = c0 + __popcll(m1);
    int s0  = __popcll(m0 & ltmask);        // my slot for row 2i   (if h0)
    int s1  = c0 + __popcll(m1 & ltmask);   // my slot for row 2i+1 (if h1)
    if (h0) { sdat[wave][s0] = make_float4(u.x, u.y, ax0, ay0); sbv[wave][s0] = b0; }
    if (h1) { sdat[wave][s1] = make_float4(u.z, u.w, ax1, ay1); sbv[wave][s1] = b1; }
    __threadfence_block();   // wave lockstep + lgkmcnt drain orders LDS w->r

    #pragma unroll 1
    for (int j = lane; j < tot; j += 64) {
        float4 d = sdat[wave][j];
        float  b = sbv[wave][j];
        sres[wave][j] = heavy_solve(d.x, d.y, d.z, d.w, b);
    }
    __threadfence_block();

    if (h0) { float2 s = sres[wave][s0]; r.x = s.x; r.y = s.y; }
    if (h1) { float2 s = sres[wave][s1]; r.z = s.x; r.w = s.y; }
    if (valid) out4[i] = r;
}

extern "C" void kernel_launch(void* const* d_in, const int* in_sizes, int n_in,
                              void* d_out, int out_size, void* d_ws, size_t ws_size,
                              hipStream_t stream) {
    const float* u_nom = (const float*)d_in[0];
    const float* obs   = (const float*)d_in[1];
    float* out = (float*)d_out;
    int rows   = in_sizes[0] / 2;     // B
    int npair  = rows / 2;            // 2 rows per thread
    int blocks = (npair + BLK - 1) / BLK;
    cbf_kernel<<<blocks, BLK, 0, stream>>>((const float4*)u_nom,
                                           (const float4*)obs,
                                           (float4*)out, npair);
}